// Round 1
// baseline (416.432 us; speedup 1.0000x reference)
//
#include <hip/hip_runtime.h>
#include <hip/hip_bf16.h>

#define D_MODEL 1024
#define NUM_HEADS 16
#define HEAD_DIM 64
#define SEQ 2048
#define BATCH 2
#define ROWS (BATCH * SEQ)  // 4096

typedef unsigned short u16;
typedef __bf16 bf16x8 __attribute__((ext_vector_type(8)));
typedef float f32x4 __attribute__((ext_vector_type(4)));

__device__ inline u16 f2bfu(float f) {
  // RNE float->bf16
  unsigned u = __float_as_uint(f);
  unsigned r = (u + 0x7fffu + ((u >> 16) & 1u)) >> 16;
  return (u16)r;
}

__device__ inline f32x4 mfma16(bf16x8 a, bf16x8 b, f32x4 c) {
  return __builtin_amdgcn_mfma_f32_16x16x32_bf16(a, b, c, 0, 0, 0);
}

__device__ inline bf16x8 lds_frag(const u16* p) {
  union { uint4 v; bf16x8 f; } u;
  u.v = *(const uint4*)p;
  return u.f;
}

// ---------------- converters ----------------

__global__ __launch_bounds__(256) void cvt_x_kernel(const float* __restrict__ x,
                                                    u16* __restrict__ y) {
  int i = blockIdx.x * 256 + threadIdx.x;  // each handles 4 floats
  float4 v = ((const float4*)x)[i];
  union { u16 s[4]; uint2 v2; } o;
  o.s[0] = f2bfu(v.x); o.s[1] = f2bfu(v.y);
  o.s[2] = f2bfu(v.z); o.s[3] = f2bfu(v.w);
  ((uint2*)y)[i] = o.v2;
}

// W [K][N] fp32 -> Wt [N][K] bf16
__global__ __launch_bounds__(256) void transpose_cvt(const float* __restrict__ W,
                                                     u16* __restrict__ Wt,
                                                     int K, int N) {
  __shared__ float t[32][33];
  int k0 = blockIdx.x * 32, n0 = blockIdx.y * 32;
  int c = threadIdx.x & 31, r8 = threadIdx.x >> 5;
#pragma unroll
  for (int i = 0; i < 4; i++) {
    int r = r8 + i * 8;
    t[r][c] = W[(size_t)(k0 + r) * N + n0 + c];
  }
  __syncthreads();
#pragma unroll
  for (int i = 0; i < 4; i++) {
    int r = r8 + i * 8;
    Wt[(size_t)(n0 + r) * K + k0 + c] = f2bfu(t[c][r]);
  }
}

// ---------------- GEMM 1: qkv = x @ W_qkv + b, scatter to Q/K/V [B,H,S,64] bf16 ----------------

__global__ __launch_bounds__(256) void gemm_qkv(const u16* __restrict__ A,   // xb [4096][1024]
                                                const u16* __restrict__ Bt,  // WqkvT [3072][1024]
                                                const float* __restrict__ bias,
                                                u16* __restrict__ Qb, u16* __restrict__ Kb,
                                                u16* __restrict__ Vb) {
  __shared__ u16 lA[64 * 64];
  __shared__ u16 lB[64 * 64];
  const int tid = threadIdx.x;
  const int wave = tid >> 6, lane = tid & 63, ln = lane & 15, quad = lane >> 4;
  const int n0 = blockIdx.x * 64, m0 = blockIdx.y * 64;
  const int wm = (wave & 1) * 32, wn = (wave >> 1) * 32;
  f32x4 zero4 = {0.f, 0.f, 0.f, 0.f};
  f32x4 acc[2][2] = {{zero4, zero4}, {zero4, zero4}};

  for (int k0 = 0; k0 < 1024; k0 += 64) {
    __syncthreads();
#pragma unroll
    for (int i = 0; i < 2; i++) {
      int c = tid + i * 256;       // chunk 0..511
      int r = c >> 3, kg = c & 7;  // row, k-group of 8
      *(uint4*)(lA + (r >> 4) * 1024 + kg * 128 + (r & 15) * 8) =
          *(const uint4*)(A + (size_t)(m0 + r) * 1024 + k0 + kg * 8);
      *(uint4*)(lB + (r >> 4) * 1024 + kg * 128 + (r & 15) * 8) =
          *(const uint4*)(Bt + (size_t)(n0 + r) * 1024 + k0 + kg * 8);
    }
    __syncthreads();
#pragma unroll
    for (int ks = 0; ks < 2; ks++) {
      bf16x8 a0 = lds_frag(lA + ((wm + 0) >> 4) * 1024 + (ks * 4 + quad) * 128 + ln * 8);
      bf16x8 a1 = lds_frag(lA + ((wm + 16) >> 4) * 1024 + (ks * 4 + quad) * 128 + ln * 8);
      bf16x8 b0 = lds_frag(lB + ((wn + 0) >> 4) * 1024 + (ks * 4 + quad) * 128 + ln * 8);
      bf16x8 b1 = lds_frag(lB + ((wn + 16) >> 4) * 1024 + (ks * 4 + quad) * 128 + ln * 8);
      acc[0][0] = mfma16(a0, b0, acc[0][0]);
      acc[0][1] = mfma16(a0, b1, acc[0][1]);
      acc[1][0] = mfma16(a1, b0, acc[1][0]);
      acc[1][1] = mfma16(a1, b1, acc[1][1]);
    }
  }
#pragma unroll
  for (int mt = 0; mt < 2; mt++)
#pragma unroll
    for (int nt = 0; nt < 2; nt++)
#pragma unroll
      for (int r = 0; r < 4; r++) {
        int row = m0 + wm + mt * 16 + quad * 4 + r;
        int col = n0 + wn + nt * 16 + ln;
        float v = acc[mt][nt][r] + bias[col];
        int h = col / 192, rem = col - h * 192, t3 = rem >> 6, d = rem & 63;
        int bb = row >> 11, s = row & 2047;
        u16* dst = (t3 == 0) ? Qb : (t3 == 1 ? Kb : Vb);
        dst[(((size_t)bb * NUM_HEADS + h) * SEQ + s) * HEAD_DIM + d] = f2bfu(v);
      }
}

// ---------------- flash attention ----------------

__global__ __launch_bounds__(256) void attn_kernel(const u16* __restrict__ Qb,
                                                   const u16* __restrict__ Kb,
                                                   const u16* __restrict__ Vb,
                                                   u16* __restrict__ Ob) {
  __shared__ u16 lQ[64 * 64];
  __shared__ u16 lK[64 * 64];
  __shared__ u16 lV[64 * 64];  // transposed fragment order
  __shared__ u16 lP[64 * 64];  // per-wave 16x64 A-frag buffers
  const int tid = threadIdx.x;
  const int wave = tid >> 6, lane = tid & 63, ln = lane & 15, quad = lane >> 4;
  const int qt = blockIdx.x;
  const int bh = blockIdx.y;
  const int q0 = qt * 64;
  const size_t base = (size_t)bh * SEQ * HEAD_DIM;
  const u16* Qg = Qb + base;
  const u16* Kg = Kb + base;
  const u16* Vg = Vb + base;

  // stage Q tile (fragment order)
#pragma unroll
  for (int i = 0; i < 2; i++) {
    int c = tid + i * 256;
    int r = c >> 3, kg = c & 7;
    *(uint4*)(lQ + (r >> 4) * 1024 + kg * 128 + (r & 15) * 8) =
        *(const uint4*)(Qg + (size_t)(q0 + r) * 64 + kg * 8);
  }
  __syncthreads();
  bf16x8 aq0 = lds_frag(lQ + wave * 1024 + (0 + quad) * 128 + ln * 8);
  bf16x8 aq1 = lds_frag(lQ + wave * 1024 + (4 + quad) * 128 + ln * 8);

  f32x4 zero4 = {0.f, 0.f, 0.f, 0.f};
  f32x4 o[4] = {zero4, zero4, zero4, zero4};
  float mrow[4], lrow[4];
#pragma unroll
  for (int r = 0; r < 4; r++) { mrow[r] = -1e30f; lrow[r] = 0.f; }

  for (int kt = 0; kt <= qt; kt++) {
    __syncthreads();
    // stage K (fragment order) and V (transposed fragment order)
#pragma unroll
    for (int i = 0; i < 2; i++) {
      int c = tid + i * 256;
      int r = c >> 3, kg = c & 7;
      *(uint4*)(lK + (r >> 4) * 1024 + kg * 128 + (r & 15) * 8) =
          *(const uint4*)(Kg + (size_t)(kt * 64 + r) * 64 + kg * 8);
      uint4 vv = *(const uint4*)(Vg + (size_t)(kt * 64 + r) * 64 + kg * 8);
      const u16* vs = (const u16*)&vv;
      int key = r, hg = kg;
      int base2 = (hg >> 1) * 1024 + (key >> 3) * 128 + (key & 7);
      int hlo = (hg & 1) * 8;
#pragma unroll
      for (int j = 0; j < 8; j++) lV[base2 + (hlo + j) * 8] = vs[j];
    }
    __syncthreads();

    // S = Q K^T * scale
    f32x4 sc[4];
#pragma unroll
    for (int nt = 0; nt < 4; nt++) {
      f32x4 s = zero4;
      bf16x8 b0 = lds_frag(lK + nt * 1024 + (0 + quad) * 128 + ln * 8);
      bf16x8 b1 = lds_frag(lK + nt * 1024 + (4 + quad) * 128 + ln * 8);
      s = mfma16(aq0, b0, s);
      s = mfma16(aq1, b1, s);
      sc[nt] = s;
    }
    const int qrow_base = q0 + wave * 16 + quad * 4;
#pragma unroll
    for (int nt = 0; nt < 4; nt++)
#pragma unroll
      for (int r = 0; r < 4; r++) sc[nt][r] = sc[nt][r] * 0.125f;
    if (kt == qt) {  // diagonal tile: causal mask
#pragma unroll
      for (int nt = 0; nt < 4; nt++) {
        int colg = kt * 64 + nt * 16 + ln;
#pragma unroll
        for (int r = 0; r < 4; r++)
          if (colg > qrow_base + r) sc[nt][r] = -1e30f;
      }
    }
    // online softmax
    float mnew[4];
#pragma unroll
    for (int r = 0; r < 4; r++) {
      float mx = fmaxf(fmaxf(sc[0][r], sc[1][r]), fmaxf(sc[2][r], sc[3][r]));
#pragma unroll
      for (int d = 1; d < 16; d <<= 1) mx = fmaxf(mx, __shfl_xor(mx, d));
      mnew[r] = fmaxf(mrow[r], mx);
    }
#pragma unroll
    for (int r = 0; r < 4; r++) {
      float sum = 0.f;
#pragma unroll
      for (int nt = 0; nt < 4; nt++) {
        float p = __expf(sc[nt][r] - mnew[r]);
        sc[nt][r] = p;
        sum += p;
      }
#pragma unroll
      for (int d = 1; d < 16; d <<= 1) sum += __shfl_xor(sum, d);
      float alpha = __expf(mrow[r] - mnew[r]);
      lrow[r] = lrow[r] * alpha + sum;
      mrow[r] = mnew[r];
#pragma unroll
      for (int c = 0; c < 4; c++) o[c][r] *= alpha;
    }
    // write P to per-wave LDS buffer in A-fragment order
    u16* lPw = lP + wave * 1024;
#pragma unroll
    for (int nt = 0; nt < 4; nt++) {
      int kbase = (nt * 2 + (ln >> 3)) * 128 + (ln & 7);
#pragma unroll
      for (int r = 0; r < 4; r++) lPw[kbase + (quad * 4 + r) * 8] = f2bfu(sc[nt][r]);
    }
    __syncthreads();
    bf16x8 ap0 = lds_frag(lPw + (0 + quad) * 128 + ln * 8);
    bf16x8 ap1 = lds_frag(lPw + (4 + quad) * 128 + ln * 8);
#pragma unroll
    for (int c = 0; c < 4; c++) {
      bf16x8 bv0 = lds_frag(lV + c * 1024 + (0 + quad) * 128 + ln * 8);
      bf16x8 bv1 = lds_frag(lV + c * 1024 + (4 + quad) * 128 + ln * 8);
      o[c] = mfma16(ap0, bv0, o[c]);
      o[c] = mfma16(ap1, bv1, o[c]);
    }
  }
  // epilogue: Ob [B][S][H*64] bf16
  const int b = bh / NUM_HEADS, h = bh - b * NUM_HEADS;
#pragma unroll
  for (int r = 0; r < 4; r++) {
    int s = q0 + wave * 16 + quad * 4 + r;
    float inv = 1.f / lrow[r];
#pragma unroll
    for (int c = 0; c < 4; c++) {
      int col = h * 64 + c * 16 + ln;
      Ob[((size_t)b * SEQ + s) * D_MODEL + col] = f2bfu(o[c][r] * inv);
    }
  }
}

// ---------------- GEMM 2: out = values @ W_out + b ----------------

__global__ __launch_bounds__(256) void gemm_out(const u16* __restrict__ A,   // values [4096][1024]
                                                const u16* __restrict__ Bt,  // WoutT [1024][1024]
                                                const float* __restrict__ bias,
                                                float* __restrict__ out) {
  __shared__ u16 lA[64 * 64];
  __shared__ u16 lB[64 * 64];
  const int tid = threadIdx.x;
  const int wave = tid >> 6, lane = tid & 63, ln = lane & 15, quad = lane >> 4;
  const int n0 = blockIdx.x * 64, m0 = blockIdx.y * 64;
  const int wm = (wave & 1) * 32, wn = (wave >> 1) * 32;
  f32x4 zero4 = {0.f, 0.f, 0.f, 0.f};
  f32x4 acc[2][2] = {{zero4, zero4}, {zero4, zero4}};

  for (int k0 = 0; k0 < 1024; k0 += 64) {
    __syncthreads();
#pragma unroll
    for (int i = 0; i < 2; i++) {
      int c = tid + i * 256;
      int r = c >> 3, kg = c & 7;
      *(uint4*)(lA + (r >> 4) * 1024 + kg * 128 + (r & 15) * 8) =
          *(const uint4*)(A + (size_t)(m0 + r) * 1024 + k0 + kg * 8);
      *(uint4*)(lB + (r >> 4) * 1024 + kg * 128 + (r & 15) * 8) =
          *(const uint4*)(Bt + (size_t)(n0 + r) * 1024 + k0 + kg * 8);
    }
    __syncthreads();
#pragma unroll
    for (int ks = 0; ks < 2; ks++) {
      bf16x8 a0 = lds_frag(lA + ((wm + 0) >> 4) * 1024 + (ks * 4 + quad) * 128 + ln * 8);
      bf16x8 a1 = lds_frag(lA + ((wm + 16) >> 4) * 1024 + (ks * 4 + quad) * 128 + ln * 8);
      bf16x8 b0 = lds_frag(lB + ((wn + 0) >> 4) * 1024 + (ks * 4 + quad) * 128 + ln * 8);
      bf16x8 b1 = lds_frag(lB + ((wn + 16) >> 4) * 1024 + (ks * 4 + quad) * 128 + ln * 8);
      acc[0][0] = mfma16(a0, b0, acc[0][0]);
      acc[0][1] = mfma16(a0, b1, acc[0][1]);
      acc[1][0] = mfma16(a1, b0, acc[1][0]);
      acc[1][1] = mfma16(a1, b1, acc[1][1]);
    }
  }
#pragma unroll
  for (int mt = 0; mt < 2; mt++)
#pragma unroll
    for (int nt = 0; nt < 2; nt++)
#pragma unroll
      for (int r = 0; r < 4; r++) {
        int row = m0 + wm + mt * 16 + quad * 4 + r;
        int col = n0 + wn + nt * 16 + ln;
        out[(size_t)row * 1024 + col] = acc[mt][nt][r] + bias[col];
      }
}

// ---------------- launcher ----------------

extern "C" void kernel_launch(void* const* d_in, const int* in_sizes, int n_in,
                              void* d_out, int out_size, void* d_ws, size_t ws_size,
                              hipStream_t stream) {
  const float* x = (const float*)d_in[0];
  const float* W_qkv = (const float*)d_in[1];
  const float* b_qkv = (const float*)d_in[2];
  const float* W_out = (const float*)d_in[3];
  const float* b_out = (const float*)d_in[4];
  float* out = (float*)d_out;

  char* ws = (char*)d_ws;
  const size_t SZ_XB = (size_t)ROWS * D_MODEL * 2;          // 8 MiB
  const size_t SZ_WQKVT = (size_t)3 * D_MODEL * D_MODEL * 2;  // 6 MiB
  const size_t SZ_WOUTT = (size_t)D_MODEL * D_MODEL * 2;      // 2 MiB
  const size_t SZ_HEADS = (size_t)BATCH * NUM_HEADS * SEQ * HEAD_DIM * 2;  // 8 MiB
  u16* xb = (u16*)(ws);
  u16* WqkvT = (u16*)(ws + SZ_XB);
  u16* WoutT = (u16*)(ws + SZ_XB + SZ_WQKVT);
  u16* Qb = (u16*)(ws + SZ_XB + SZ_WQKVT + SZ_WOUTT);
  u16* Kb = (u16*)(ws + SZ_XB + SZ_WQKVT + SZ_WOUTT + SZ_HEADS);
  u16* Vb = (u16*)(ws + SZ_XB + SZ_WQKVT + SZ_WOUTT + 2 * SZ_HEADS);
  u16* Ob = (u16*)(ws + SZ_XB + SZ_WQKVT + SZ_WOUTT + 3 * SZ_HEADS);

  cvt_x_kernel<<<dim3(ROWS * D_MODEL / 4 / 256), dim3(256), 0, stream>>>(x, xb);
  transpose_cvt<<<dim3(D_MODEL / 32, 3 * D_MODEL / 32), dim3(256), 0, stream>>>(W_qkv, WqkvT,
                                                                                D_MODEL, 3 * D_MODEL);
  transpose_cvt<<<dim3(D_MODEL / 32, D_MODEL / 32), dim3(256), 0, stream>>>(W_out, WoutT,
                                                                            D_MODEL, D_MODEL);
  gemm_qkv<<<dim3(3 * D_MODEL / 64, ROWS / 64), dim3(256), 0, stream>>>(xb, WqkvT, b_qkv, Qb, Kb, Vb);
  attn_kernel<<<dim3(SEQ / 64, BATCH * NUM_HEADS), dim3(256), 0, stream>>>(Qb, Kb, Vb, Ob);
  gemm_out<<<dim3(D_MODEL / 64, ROWS / 64), dim3(256), 0, stream>>>(Ob, WoutT, b_out, out);
}

// Round 4
// 303.465 us; speedup vs baseline: 1.3723x; 1.3723x over previous
//
#include <hip/hip_runtime.h>
#include <hip/hip_bf16.h>

#define D_MODEL 1024
#define NUM_HEADS 16
#define HEAD_DIM 64
#define SEQ 2048
#define BATCH 2
#define ROWS (BATCH * SEQ)  // 4096

typedef unsigned short u16;
typedef __bf16 bf16x8 __attribute__((ext_vector_type(8)));
typedef float f32x4 __attribute__((ext_vector_type(4)));

__device__ inline u16 f2bfu(float f) {
  // RNE float->bf16
  unsigned u = __float_as_uint(f);
  unsigned r = (u + 0x7fffu + ((u >> 16) & 1u)) >> 16;
  return (u16)r;
}

__device__ inline f32x4 mfma16(bf16x8 a, bf16x8 b, f32x4 c) {
  return __builtin_amdgcn_mfma_f32_16x16x32_bf16(a, b, c, 0, 0, 0);
}

__device__ inline bf16x8 load_frag(const u16* p) {
  union { uint4 v; bf16x8 f; } u;
  u.v = *(const uint4*)p;
  return u.f;
}

// async global->LDS, 16B per lane; LDS dest = wave-uniform base + lane*16
__device__ inline void gload_lds16(const u16* g, u16* l) {
  __builtin_amdgcn_global_load_lds((const __attribute__((address_space(1))) void*)g,
                                   (__attribute__((address_space(3))) void*)l, 16, 0, 0);
}

// ---------------- converters ----------------

__global__ __launch_bounds__(256) void cvt_x_kernel(const float* __restrict__ x,
                                                    u16* __restrict__ y) {
  int i = blockIdx.x * 256 + threadIdx.x;  // each handles 4 floats
  float4 v = ((const float4*)x)[i];
  union { u16 s[4]; uint2 v2; } o;
  o.s[0] = f2bfu(v.x); o.s[1] = f2bfu(v.y);
  o.s[2] = f2bfu(v.z); o.s[3] = f2bfu(v.w);
  ((uint2*)y)[i] = o.v2;
}

// W [K][N] fp32 -> Wt [N][K] bf16
__global__ __launch_bounds__(256) void transpose_cvt(const float* __restrict__ W,
                                                     u16* __restrict__ Wt,
                                                     int K, int N) {
  __shared__ float t[32][33];
  int k0 = blockIdx.x * 32, n0 = blockIdx.y * 32;
  int c = threadIdx.x & 31, r8 = threadIdx.x >> 5;
#pragma unroll
  for (int i = 0; i < 4; i++) {
    int r = r8 + i * 8;
    t[r][c] = W[(size_t)(k0 + r) * N + n0 + c];
  }
  __syncthreads();
#pragma unroll
  for (int i = 0; i < 4; i++) {
    int r = r8 + i * 8;
    Wt[(size_t)(n0 + r) * K + k0 + c] = f2bfu(t[c][r]);
  }
}

// ---------------- GEMM 1: qkv = x @ W_qkv + b -> Qb/Kb [bh][s][64], Vt [bh][d][s] ----------------
// 128x128 tile, BK=64, global_load_lds width=16, fragment-ordered LDS.
// LDS layout: 16-row block = 16 rows x 64 k = 1024 u16 (block stride 1024!),
// granule kg (8 k) at kg*128, row-in-block at ln*8.

__global__ __launch_bounds__(256) void gemm_qkv(const u16* __restrict__ A,   // xb [4096][1024]
                                                const u16* __restrict__ Bt,  // WqkvT [3072][1024]
                                                const float* __restrict__ bias,
                                                u16* __restrict__ Qb, u16* __restrict__ Kb,
                                                u16* __restrict__ Vt) {
  __shared__ u16 lA[128 * 64];
  __shared__ u16 lB[128 * 64];
  const int tid = threadIdx.x;
  const int wave = tid >> 6, lane = tid & 63, ln = lane & 15, quad = lane >> 4;
  const int n0 = blockIdx.x * 128, m0 = blockIdx.y * 128;
  const int wm = (wave & 1) * 64, wn = (wave >> 1) * 64;
  f32x4 acc[4][4] = {};

  for (int kt = 0; kt < 16; ++kt) {
    const int k0 = kt * 64;
    __syncthreads();
#pragma unroll
    for (int i = 0; i < 4; ++i) {
      int c = wave * 4 + i;  // 16 chunks of 1KB each for A and B
      int rb = c >> 1, kgh = c & 1;
      gload_lds16(A + (size_t)(m0 + rb * 16 + ln) * 1024 + k0 + (kgh * 4 + quad) * 8,
                  lA + rb * 1024 + kgh * 512);
      gload_lds16(Bt + (size_t)(n0 + rb * 16 + ln) * 1024 + k0 + (kgh * 4 + quad) * 8,
                  lB + rb * 1024 + kgh * 512);
    }
    __syncthreads();
#pragma unroll
    for (int ks = 0; ks < 2; ++ks) {
      bf16x8 a[4], b[4];
#pragma unroll
      for (int i = 0; i < 4; ++i) {
        a[i] = load_frag(lA + (wm / 16 + i) * 1024 + (ks * 4 + quad) * 128 + ln * 8);
        b[i] = load_frag(lB + (wn / 16 + i) * 1024 + (ks * 4 + quad) * 128 + ln * 8);
      }
#pragma unroll
      for (int mt = 0; mt < 4; ++mt)
#pragma unroll
        for (int nt = 0; nt < 4; ++nt) acc[mt][nt] = mfma16(a[mt], b[nt], acc[mt][nt]);
    }
  }
#pragma unroll
  for (int mt = 0; mt < 4; ++mt) {
    int row = m0 + wm + mt * 16 + quad * 4;
    int bb = row >> 11, s0 = row & 2047;
#pragma unroll
    for (int nt = 0; nt < 4; ++nt) {
      int col = n0 + wn + nt * 16 + ln;
      float bv = bias[col];
      int h = col / 192, rem = col - h * 192, t3 = rem >> 6, d = rem & 63;
      int bh = bb * NUM_HEADS + h;
      if (t3 == 2) {  // V -> transposed layout [bh][d][s], 4 consecutive s packed
        union { u16 s[4]; uint2 v; } pk;
#pragma unroll
        for (int r = 0; r < 4; ++r) pk.s[r] = f2bfu(acc[mt][nt][r] + bv);
        *(uint2*)(Vt + ((size_t)bh * 64 + d) * SEQ + s0) = pk.v;
      } else {
        u16* dst = (t3 == 0) ? Qb : Kb;
#pragma unroll
        for (int r = 0; r < 4; ++r)
          dst[((size_t)bh * SEQ + s0 + r) * 64 + d] = f2bfu(acc[mt][nt][r] + bv);
      }
    }
  }
}

// ---------------- flash attention, S^T formulation, 1 wave / 32 q-rows, no barriers ----------------
// S^T = K·Q^T  (A-frag = K rows from global, B-frag = Q rows from global)
// O^T = V^T·P^T (A-frag = Vt rows from global, B-frag = P via per-wave swizzled LDS)

__global__ __launch_bounds__(64) void attn_kernel(const u16* __restrict__ Qb,
                                                  const u16* __restrict__ Kb,
                                                  const u16* __restrict__ Vt,
                                                  u16* __restrict__ Ob) {
  __shared__ u16 lbuf[32 * 72];  // P: 32q x 64k swizzled (first 2048); epilogue: 32q x 72 stride
  const int lane = threadIdx.x & 63;
  const int ln = lane & 15, quad = lane >> 4;
  const int q0 = blockIdx.x * 32;
  const int bh = blockIdx.y;
  const u16* Qg = Qb + (size_t)bh * SEQ * 64;
  const u16* Kg = Kb + (size_t)bh * SEQ * 64;
  const u16* Vg = Vt + (size_t)bh * 64 * SEQ;

  // Q B-frags, loaded once: qf[nq][ks] = Q[q0+nq*16+ln][ks*32+quad*8 ..+8]
  bf16x8 qf[2][2];
#pragma unroll
  for (int nq = 0; nq < 2; ++nq)
#pragma unroll
    for (int ks = 0; ks < 2; ++ks)
      qf[nq][ks] = load_frag(Qg + (size_t)(q0 + nq * 16 + ln) * 64 + ks * 32 + quad * 8);

  f32x4 o[4][2] = {};                      // O^T: row d=dt*16+quad*4+r, col q=nq*16+ln
  float m_r[2] = {-1e30f, -1e30f};         // per-lane: q = q0+nq*16+ln (exp2 domain)
  float l_r[2] = {0.f, 0.f};
  const int kt_max = (q0 + 31) >> 6;

  for (int kt = 0; kt <= kt_max; ++kt) {
    // S^T tile: 64 keys x 32 q
    f32x4 sc[4][2] = {};
#pragma unroll
    for (int mt = 0; mt < 4; ++mt) {
      const u16* kr = Kg + (size_t)(kt * 64 + mt * 16 + ln) * 64;
      bf16x8 kf0 = load_frag(kr + quad * 8);
      bf16x8 kf1 = load_frag(kr + 32 + quad * 8);
#pragma unroll
      for (int nq = 0; nq < 2; ++nq) {
        sc[mt][nq] = mfma16(kf0, qf[nq][0], sc[mt][nq]);
        sc[mt][nq] = mfma16(kf1, qf[nq][1], sc[mt][nq]);
      }
    }
    const float SC = 0.18033688011112042f;  // log2(e) / sqrt(64)  (exp2 domain)
    const bool diag = (kt == kt_max);
#pragma unroll
    for (int nq = 0; nq < 2; ++nq) {
      const int qq = q0 + nq * 16 + ln;
      // scale + causal mask (only diagonal tile can mask)
#pragma unroll
      for (int mt = 0; mt < 4; ++mt) {
        int key0 = kt * 64 + mt * 16 + quad * 4;
#pragma unroll
        for (int r = 0; r < 4; ++r) {
          float v = sc[mt][nq][r] * SC;
          if (diag && (key0 + r > qq)) v = -1e30f;
          sc[mt][nq][r] = v;
        }
      }
      // online softmax: 16 in-lane values + butterfly over quads (lanes ^16, ^32)
      float mloc = sc[0][nq][0];
#pragma unroll
      for (int mt = 0; mt < 4; ++mt)
#pragma unroll
        for (int r = 0; r < 4; ++r) mloc = fmaxf(mloc, sc[mt][nq][r]);
      mloc = fmaxf(mloc, __shfl_xor(mloc, 16));
      mloc = fmaxf(mloc, __shfl_xor(mloc, 32));
      float mnew = fmaxf(m_r[nq], mloc);
      float alpha = __builtin_amdgcn_exp2f(m_r[nq] - mnew);
      float sum = 0.f;
#pragma unroll
      for (int mt = 0; mt < 4; ++mt)
#pragma unroll
        for (int r = 0; r < 4; ++r) {
          float p = __builtin_amdgcn_exp2f(sc[mt][nq][r] - mnew);
          sc[mt][nq][r] = p;
          sum += p;
        }
      sum += __shfl_xor(sum, 16);
      sum += __shfl_xor(sum, 32);
      l_r[nq] = l_r[nq] * alpha + sum;
      m_r[nq] = mnew;
#pragma unroll
      for (int dt = 0; dt < 4; ++dt) o[dt][nq] *= alpha;
    }
    // P -> per-wave LDS, [q][k] with k-granule XOR swizzle (bank-spread), packed b64 writes
#pragma unroll
    for (int nq = 0; nq < 2; ++nq)
#pragma unroll
      for (int mt = 0; mt < 4; ++mt) {
        union { u16 s[4]; uint2 v; } pk;
#pragma unroll
        for (int r = 0; r < 4; ++r) pk.s[r] = f2bfu(sc[mt][nq][r]);
        int addr = (nq * 16 + ln) * 64 + (((mt * 2 + (quad >> 1)) ^ (ln & 7)) * 8) + (quad & 1) * 4;
        *(uint2*)(lbuf + addr) = pk.v;
      }
    asm volatile("s_waitcnt lgkmcnt(0)" ::: "memory");  // wave-internal RAW; LDS is in-order per wave
    bf16x8 pf[2][2];
#pragma unroll
    for (int ks = 0; ks < 2; ++ks)
#pragma unroll
      for (int nq = 0; nq < 2; ++nq)
        pf[ks][nq] = load_frag(lbuf + (nq * 16 + ln) * 64 + (((ks * 4 + quad) ^ (ln & 7)) * 8));
    // O^T += V^T · P^T
#pragma unroll
    for (int dt = 0; dt < 4; ++dt) {
#pragma unroll
      for (int ks = 0; ks < 2; ++ks) {
        bf16x8 av = load_frag(Vg + (size_t)(dt * 16 + ln) * SEQ + kt * 64 + ks * 32 + quad * 8);
#pragma unroll
        for (int nq = 0; nq < 2; ++nq) o[dt][nq] = mfma16(av, pf[ks][nq], o[dt][nq]);
      }
    }
  }

  // epilogue: normalize, transpose O^T -> [q][d] via LDS, coalesced 16B stores
  float inv0 = 1.f / l_r[0], inv1 = 1.f / l_r[1];
  asm volatile("s_waitcnt lgkmcnt(0)" ::: "memory");
#pragma unroll
  for (int nq = 0; nq < 2; ++nq) {
    float inv = nq ? inv1 : inv0;
#pragma unroll
    for (int dt = 0; dt < 4; ++dt) {
      union { u16 s[4]; uint2 v; } pk;
#pragma unroll
      for (int r = 0; r < 4; ++r) pk.s[r] = f2bfu(o[dt][nq][r] * inv);
      *(uint2*)(lbuf + (nq * 16 + ln) * 72 + dt * 16 + quad * 4) = pk.v;
    }
  }
  asm volatile("s_waitcnt lgkmcnt(0)" ::: "memory");
  const int b = bh >> 4, h = bh & 15;
#pragma unroll
  for (int i = 0; i < 4; ++i) {
    int c = lane + i * 64;
    int qq = c >> 3, dg = c & 7;
    uint4 val = *(const uint4*)(lbuf + qq * 72 + dg * 8);
    *(uint4*)(Ob + ((size_t)b * SEQ + q0 + qq) * 1024 + h * 64 + dg * 8) = val;
  }
}

// ---------------- GEMM 2: out = values @ W_out + b (fp32 out) ----------------

__global__ __launch_bounds__(256) void gemm_out(const u16* __restrict__ A,   // Ob [4096][1024]
                                                const u16* __restrict__ Bt,  // WoutT [1024][1024]
                                                const float* __restrict__ bias,
                                                float* __restrict__ out) {
  __shared__ u16 lA[128 * 64];
  __shared__ u16 lB[128 * 64];
  const int tid = threadIdx.x;
  const int wave = tid >> 6, lane = tid & 63, ln = lane & 15, quad = lane >> 4;
  const int n0 = blockIdx.x * 128, m0 = blockIdx.y * 128;
  const int wm = (wave & 1) * 64, wn = (wave >> 1) * 64;
  f32x4 acc[4][4] = {};

  for (int kt = 0; kt < 16; ++kt) {
    const int k0 = kt * 64;
    __syncthreads();
#pragma unroll
    for (int i = 0; i < 4; ++i) {
      int c = wave * 4 + i;
      int rb = c >> 1, kgh = c & 1;
      gload_lds16(A + (size_t)(m0 + rb * 16 + ln) * 1024 + k0 + (kgh * 4 + quad) * 8,
                  lA + rb * 1024 + kgh * 512);
      gload_lds16(Bt + (size_t)(n0 + rb * 16 + ln) * 1024 + k0 + (kgh * 4 + quad) * 8,
                  lB + rb * 1024 + kgh * 512);
    }
    __syncthreads();
#pragma unroll
    for (int ks = 0; ks < 2; ++ks) {
      bf16x8 a[4], b[4];
#pragma unroll
      for (int i = 0; i < 4; ++i) {
        a[i] = load_frag(lA + (wm / 16 + i) * 1024 + (ks * 4 + quad) * 128 + ln * 8);
        b[i] = load_frag(lB + (wn / 16 + i) * 1024 + (ks * 4 + quad) * 128 + ln * 8);
      }
#pragma unroll
      for (int mt = 0; mt < 4; ++mt)
#pragma unroll
        for (int nt = 0; nt < 4; ++nt) acc[mt][nt] = mfma16(a[mt], b[nt], acc[mt][nt]);
    }
  }
#pragma unroll
  for (int mt = 0; mt < 4; ++mt) {
    int row = m0 + wm + mt * 16 + quad * 4;
#pragma unroll
    for (int nt = 0; nt < 4; ++nt) {
      int col = n0 + wn + nt * 16 + ln;
      float bv = bias[col];
#pragma unroll
      for (int r = 0; r < 4; ++r)
        out[(size_t)(row + r) * 1024 + col] = acc[mt][nt][r] + bv;
    }
  }
}

// ---------------- launcher ----------------

extern "C" void kernel_launch(void* const* d_in, const int* in_sizes, int n_in,
                              void* d_out, int out_size, void* d_ws, size_t ws_size,
                              hipStream_t stream) {
  const float* x = (const float*)d_in[0];
  const float* W_qkv = (const float*)d_in[1];
  const float* b_qkv = (const float*)d_in[2];
  const float* W_out = (const float*)d_in[3];
  const float* b_out = (const float*)d_in[4];
  float* out = (float*)d_out;

  char* ws = (char*)d_ws;
  const size_t SZ_XB = (size_t)ROWS * D_MODEL * 2;            // 8 MiB
  const size_t SZ_WQKVT = (size_t)3 * D_MODEL * D_MODEL * 2;  // 6 MiB
  const size_t SZ_WOUTT = (size_t)D_MODEL * D_MODEL * 2;      // 2 MiB
  const size_t SZ_HEADS = (size_t)BATCH * NUM_HEADS * SEQ * HEAD_DIM * 2;  // 8 MiB
  u16* xb = (u16*)(ws);
  u16* WqkvT = (u16*)(ws + SZ_XB);
  u16* WoutT = (u16*)(ws + SZ_XB + SZ_WQKVT);
  u16* Qb = (u16*)(ws + SZ_XB + SZ_WQKVT + SZ_WOUTT);
  u16* Kb = (u16*)(ws + SZ_XB + SZ_WQKVT + SZ_WOUTT + SZ_HEADS);
  u16* Vt = (u16*)(ws + SZ_XB + SZ_WQKVT + SZ_WOUTT + 2 * SZ_HEADS);
  u16* Ob = (u16*)(ws + SZ_XB + SZ_WQKVT + SZ_WOUTT + 3 * SZ_HEADS);

  cvt_x_kernel<<<dim3(ROWS * D_MODEL / 4 / 256), dim3(256), 0, stream>>>(x, xb);
  transpose_cvt<<<dim3(D_MODEL / 32, 3 * D_MODEL / 32), dim3(256), 0, stream>>>(W_qkv, WqkvT,
                                                                                D_MODEL, 3 * D_MODEL);
  transpose_cvt<<<dim3(D_MODEL / 32, D_MODEL / 32), dim3(256), 0, stream>>>(W_out, WoutT,
                                                                            D_MODEL, D_MODEL);
  gemm_qkv<<<dim3(3 * D_MODEL / 128, ROWS / 128), dim3(256), 0, stream>>>(xb, WqkvT, b_qkv,
                                                                          Qb, Kb, Vt);
  attn_kernel<<<dim3(SEQ / 32, BATCH * NUM_HEADS), dim3(64), 0, stream>>>(Qb, Kb, Vt, Ob);
  gemm_out<<<dim3(D_MODEL / 128, ROWS / 128), dim3(256), 0, stream>>>(Ob, WoutT, b_out, out);
}